// Round 5
// baseline (1664.469 us; speedup 1.0000x reference)
//
#include <hip/hip_runtime.h>
#include <hip/hip_bf16.h>

typedef unsigned short ushort_t;
typedef __attribute__((ext_vector_type(8))) short short8v;
typedef __attribute__((ext_vector_type(4))) float f32x4;

__device__ __forceinline__ ushort_t f2bs(float v) {
  union { __hip_bfloat16 h; ushort_t u; } cv;
  cv.h = __float2bfloat16(v);
  return cv.u;
}
__device__ __forceinline__ float bs2f(ushort_t u) {
  union { ushort_t u; __hip_bfloat16 h; } cv;
  cv.u = u;
  return __bfloat162float(cv.h);
}

// ---------------- workspace layout ----------------
static constexpr size_t OFF_P = 0;
static constexpr size_t OFF_ENORM = 4194304;
static constexpr size_t OFF_WTD2 = 4194816;
static constexpr size_t OFF_ACC = 4207360;
static constexpr size_t OFF_ZROW = 4207368;
static constexpr size_t OFF_EMBT = 4207432;   // fp32 embT [c=256][code=512]
static constexpr size_t OFF_SSQ = 4338504;    // 8 slots x 256 samples
static constexpr size_t OFF_SHORT = 4340552;  // 16B aligned (x4 bytes)
static constexpr size_t SO_H1H = 0;
static constexpr size_t SO_H1L = 16777216;
static constexpr size_t SO_NBH = 33554432;
static constexpr size_t SO_NBL = 37748736;
static constexpr size_t SO_W1H = 41943040;
static constexpr size_t SO_W1L = 41959424;
static constexpr size_t SO_W2H = 41975808;
static constexpr size_t SO_W2L = 43024384;
static constexpr size_t SO_W3EH = 44072960;
static constexpr size_t SO_W3EL = 45252608;
static constexpr size_t SO_W3D = 46432256;
static constexpr size_t SO_W1REH = 47611904;
static constexpr size_t SO_W1REL = 47742976;
static constexpr size_t SO_W1RD = 47874048;
static constexpr size_t SO_WD1 = 48005120;

__device__ __forceinline__ void split_store(float v, ushort_t* hi, ushort_t* lo, size_t i) {
  ushort_t h = f2bs(v);
  hi[i] = h;
  lo[i] = f2bs(v - bs2f(h));
}

// ---------------- fused prep ----------------
// ranges: [0,64) w1 | [64,4160) w2 | [4160,8768) w3e | [8768,13376) w3d
// [13376,13888) w1re | [13888,14400) w1rd | [14400,18496) wd1 | [18496,18544) dec2
// [18544,18546) enorm | 18546 zero | [18547,34931) conv1 im2col (16384 blocks EXACT)
// [34931,35443) embT
__global__ void __launch_bounds__(256) k_prep(
    const float* __restrict__ x, const float* __restrict__ ew1,
    const float* __restrict__ ew2, const float* __restrict__ r3w,
    const float* __restrict__ r1w, const float* __restrict__ dw1,
    const float* __restrict__ dw2, const float* __restrict__ emb,
    ushort_t* __restrict__ W1H, ushort_t* __restrict__ W1L,
    ushort_t* __restrict__ W2H, ushort_t* __restrict__ W2L,
    ushort_t* __restrict__ W3EH, ushort_t* __restrict__ W3EL,
    ushort_t* __restrict__ W3D, ushort_t* __restrict__ W1REH,
    ushort_t* __restrict__ W1REL, ushort_t* __restrict__ W1RD,
    ushort_t* __restrict__ WD1, float* __restrict__ wTd2,
    float* __restrict__ enorm, float* __restrict__ acc, float* __restrict__ zrow,
    float* __restrict__ embT, float* __restrict__ ssq,
    ushort_t* __restrict__ A1H, ushort_t* __restrict__ A1L) {
  int b = blockIdx.x, t = threadIdx.x;
  if (b < 64) {
    int i = b * 256 + t;
    int oc = i >> 6, k = i & 63;
    float v = 0.f;
    if (k < 48) {
      int tap = k / 3, ic = k - 3 * tap;
      v = ew1[(oc * 3 + ic) * 16 + tap];
    }
    split_store(v, W1H, W1L, i);
  } else if (b < 4160) {
    int i = (b - 64) * 256 + t;
    int oc = i >> 12, k = i & 4095;
    int tap = k >> 8, ic = k & 255;
    split_store(ew2[(oc * 256 + ic) * 16 + tap], W2H, W2L, i);
  } else if (b < 8768) {
    int i = (b - 4160) * 256 + t;
    int rb = i / 589824, r2 = i - rb * 589824;
    int oc = r2 / 2304, k = r2 - oc * 2304;
    int r9 = k >> 8, ic = k & 255;
    split_store(r3w[((rb * 256 + oc) * 256 + ic) * 9 + r9], W3EH, W3EL, i);
  } else if (b < 13376) {
    int i = (b - 8768) * 256 + t;
    int rb = i / 589824, r2 = i - rb * 589824;
    int oc = r2 / 2304, k = r2 - oc * 2304;
    int r9 = k >> 8, ic = k & 255;
    W3D[i] = f2bs(r3w[(((rb + 2) * 256 + oc) * 256 + ic) * 9 + r9]);
  } else if (b < 13888) {
    int i = (b - 13376) * 256 + t;
    split_store(r1w[i], W1REH, W1REL, i);
  } else if (b < 14400) {
    int i = (b - 13888) * 256 + t;
    W1RD[i] = f2bs(r1w[2 * 65536 + i]);
  } else if (b < 18496) {
    int i = (b - 14400) * 256 + t;
    int cls = i >> 18, r2 = i & 262143;
    int oc = r2 >> 10, k = r2 & 1023;
    int tap = k >> 8, ic = k & 255;
    int s = tap >> 1, sx = tap & 1;
    int py = cls >> 1, px = cls & 1;
    int ky = py + 2 - 2 * s, kx = px + 2 - 2 * sx;
    WD1[i] = f2bs(dw1[(ic * 256 + oc) * 16 + ky * 4 + kx]);
  } else if (b < 18544) {
    int i = (b - 18496) * 256 + t;
    if (i < 12288) {
      int kyx = i & 15;
      int r = i >> 4;
      int oc = r % 3;
      int ic = r / 3;
      wTd2[(ic * 16 + kyx) * 3 + oc] = dw2[i];
    }
  } else if (b < 18546) {
    int e = (b - 18544) * 256 + t;
    float s = 0.f;
    for (int c = 0; c < 256; ++c) {
      float v = emb[e * 256 + c];
      s += v * v;
    }
    enorm[e] = s;
  } else if (b == 18546) {
    if (t < 2) acc[t] = 0.f;
    if (t < 64) zrow[t] = 0.f;
    for (int k = t; k < 2048; k += 256) ssq[k] = 0.f;
  } else if (b < 34931) {  // conv1 im2col: exactly 16384 blocks
    int i = (b - 18547) * 256 + t;
    int t1 = i >> 6, k = i & 63;
    float v = 0.f;
    if (k < 48) {
      int tap = k / 3, ic = k - 3 * tap;
      int n = t1 >> 8, oy = (t1 >> 4) & 15, ox = t1 & 15;
      int ky = tap >> 2, kx = tap & 3;
      int iy = 2 * oy - 1 + ky, ix = 2 * ox - 1 + kx;
      if ((unsigned)iy < 32u && (unsigned)ix < 32u)
        v = x[((n * 3 + ic) * 32 + iy) * 32 + ix];
    }
    split_store(v, A1H, A1L, i);
  } else {  // [34931, 35443): embT [c][code] fp32
    int i = (b - 34931) * 256 + t;
    int code = i >> 8, c = i & 255;
    embT[c * 512 + code] = emb[i];
  }
}

// ---------------- MFMA GEMM (direct-from-global fragments; no LDS/barriers) --
// BM=128, BN=64, 4 waves, wave tile 64x32. Each lane loads its MFMA fragment
// straight from global: row = base + (l&15), k = kk + (l>>4)*8, one 16B
// vector per lane (16 fully-used 64B segments per wave-load, L2/L3-hot).
// Fragment rows are wave-exclusive, so the LDS round-trip (glds16 write +
// ds_read_b128 + barrier lockstep) that consumed ~40% of the per-step pipe
// budget in rounds 0-4 is deleted; waves free-run and the compiler pipelines
// the loads across K-steps with its own counted vmcnt.
// Per-tap im2col bases (MODE 1/2/3) recomputed only when (kk&255)==0.
// SSQ=1 (EPI 1/2 only): per-wave sum of stored^2 -> atomicAdd(ssqp[sample]).
template <int MODE, int EPI, int STYLE, int SWZ, int SSQ>
__global__ __launch_bounds__(256) void k_gemm(const ushort_t* __restrict__ Ah,
                                              const ushort_t* __restrict__ Al,
                                              const ushort_t* __restrict__ Bh,
                                              const ushort_t* __restrict__ Bl, int K,
                                              const float* __restrict__ bias,
                                              const float* __restrict__ res,
                                              float* __restrict__ outf,
                                              ushort_t* __restrict__ outb,
                                              ushort_t* __restrict__ outb2,
                                              const ushort_t* __restrict__ zrow,
                                              float* __restrict__ ssqp) {
  const int t = threadIdx.x;
  const int w = t >> 6, l = t & 63;
  int M0, N0;
  if (SWZ) {
    int b = blockIdx.x;
    M0 = (((b >> 5) << 3) | (b & 7)) * 128;
    N0 = ((b >> 3) & 3) * 64;
  } else {
    M0 = blockIdx.x * 128;
    N0 = blockIdx.y * 64;
  }
  int py = 0, px = 0;
  const ushort_t* Bb = Bh;
  if (MODE == 3) {
    int cls = blockIdx.z;
    py = cls >> 1;
    px = cls & 1;
    Bb = Bh + (size_t)cls * 262144;
  }
  const int fr = l & 15, quad = l >> 4;
  const int quad8 = quad * 8;
  const int m_off = (w & 1) * 64, n_off = (w >> 1) * 32;

  f32x4 acc[4][2];
#pragma unroll
  for (int i = 0; i < 4; ++i)
#pragma unroll
    for (int j = 0; j < 2; ++j) acc[i][j] = (f32x4){0.f, 0.f, 0.f, 0.f};

  // per-lane A fragment rows (4 M-subtiles)
  int nnr[4], oyr[4], oxr[4];
  size_t a0b[4];   // MODE 0: row*K + quad8
  size_t rbase[4]; // MODE 1/2/3: per-tap row base (elements)
  bool vld[4];
#pragma unroll
  for (int mi = 0; mi < 4; ++mi) {
    int tok = M0 + m_off + mi * 16 + fr;
    nnr[mi] = tok >> 6;
    oyr[mi] = (tok >> 3) & 7;
    oxr[mi] = tok & 7;
    a0b[mi] = (size_t)tok * K + quad8;
    rbase[mi] = 0;
    vld[mi] = true;
  }
  // per-lane B fragment rows (2 N-subtiles)
  const ushort_t *pb0[2], *pb1[2];
#pragma unroll
  for (int nj = 0; nj < 2; ++nj) {
    size_t bo = (size_t)(N0 + n_off + nj * 16 + fr) * K + quad8;
    pb0[nj] = Bb + bo;
    pb1[nj] = (STYLE == 1) ? (Bl + bo) : (Bb + bo + 32);
  }
  const ushort_t* zp = zrow + quad8;

  const int SUB = (STYLE == 1) ? 32 : 64;

  for (int kk = 0; kk < K; kk += SUB) {
    if (MODE != 0 && (kk & 255) == 0) {
      int tap = kk >> 8;
#pragma unroll
      for (int mi = 0; mi < 4; ++mi) {
        int iy, ix;
        unsigned lim;
        if (MODE == 1) {
          int ky = tap >> 2, kx = tap & 3;
          iy = 2 * oyr[mi] - 1 + ky; ix = 2 * oxr[mi] - 1 + kx;
          lim = 16u;
        } else if (MODE == 2) {
          int ky = tap / 3, kx = tap - ky * 3;
          iy = oyr[mi] - 1 + ky; ix = oxr[mi] - 1 + kx;
          lim = 8u;
        } else {
          int s2 = tap >> 1, sx = tap & 1;
          iy = oyr[mi] + s2 - py; ix = oxr[mi] + sx - px;
          lim = 8u;
        }
        vld[mi] = ((unsigned)iy < lim && (unsigned)ix < lim);
        if (MODE == 1)
          rbase[mi] = (size_t)(((nnr[mi] << 8) + (iy << 4) + ix)) << 8;
        else
          rbase[mi] = (size_t)(((nnr[mi] << 6) + (iy << 3) + ix)) << 8;
      }
    }
    short8v af0[4], af1[4], bf0[2], bf1[2];
#pragma unroll
    for (int mi = 0; mi < 4; ++mi) {
      const ushort_t *p, *q;
      if (MODE == 0) {
        p = Ah + a0b[mi] + kk;
        q = (STYLE == 1) ? (Al + a0b[mi] + kk) : (p + 32);
      } else {
        int kin = (kk & 255) + quad8;
        p = vld[mi] ? (Ah + rbase[mi] + kin) : zp;
        if (STYLE == 1)
          q = vld[mi] ? (Al + rbase[mi] + kin) : zp;
        else
          q = vld[mi] ? (Ah + rbase[mi] + kin + 32) : zp;
      }
      af0[mi] = *(const short8v*)p;
      af1[mi] = *(const short8v*)q;
    }
#pragma unroll
    for (int nj = 0; nj < 2; ++nj) {
      bf0[nj] = *(const short8v*)(pb0[nj] + kk);
      bf1[nj] = *(const short8v*)(pb1[nj] + kk);
    }
#pragma unroll
    for (int mi = 0; mi < 4; ++mi)
#pragma unroll
      for (int nj = 0; nj < 2; ++nj) {
        acc[mi][nj] =
            __builtin_amdgcn_mfma_f32_16x16x32_bf16(af0[mi], bf0[nj], acc[mi][nj], 0, 0, 0);
        if (STYLE == 1) {
          acc[mi][nj] =
              __builtin_amdgcn_mfma_f32_16x16x32_bf16(af1[mi], bf0[nj], acc[mi][nj], 0, 0, 0);
          acc[mi][nj] =
              __builtin_amdgcn_mfma_f32_16x16x32_bf16(af0[mi], bf1[nj], acc[mi][nj], 0, 0, 0);
        } else {
          acc[mi][nj] =
              __builtin_amdgcn_mfma_f32_16x16x32_bf16(af1[mi], bf1[nj], acc[mi][nj], 0, 0, 0);
        }
      }
  }

  float sq = 0.f;
#pragma unroll
  for (int mi = 0; mi < 4; ++mi) {
    int mrow = m_off + mi * 16 + quad * 4;
#pragma unroll
    for (int nj = 0; nj < 2; ++nj) {
      int col = N0 + n_off + nj * 16 + fr;
      float bv = bias[col];
#pragma unroll
      for (int i = 0; i < 4; ++i) {
        int m = M0 + mrow + i;
        float v = fmaxf(acc[mi][nj][i] + bv, 0.f);
        if (EPI == 1) {
          outf[(size_t)m * 256 + col] = v;
          if (SSQ) sq += v * v;
        } else if (EPI == 2) {
          size_t o = (size_t)m * 256 + col;
          float vv = res[o] + v;
          outf[o] = vv;
          if (SSQ) sq += vv * vv;
        } else if (EPI == 3) {
          int nn = m >> 6, jj = (m >> 3) & 7, ii = m & 7;
          int oy = 2 * jj + 1 - py, ox = 2 * ii + 1 - px;
          outb[(size_t)((nn << 8) + oy * 16 + ox) * 256 + col] = f2bs(v);
        } else if (EPI == 4) {
          size_t o = (size_t)m * 256 + col;
          ushort_t h = f2bs(v);
          outb[o] = h;
          outb2[o] = f2bs(v - bs2f(h));
        } else {  // EPI 5
          size_t o = (size_t)m * 256 + col;
          float vv = res[o] + v;
          outf[o] = vv;
          outb[o] = f2bs(vv);
        }
      }
    }
  }
  if (SSQ) {
#pragma unroll
    for (int off = 32; off > 0; off >>= 1) sq += __shfl_down(sq, off, 64);
    if (l == 0) atomicAdd(&ssqp[(M0 >> 6) + (w & 1)], sq);
  }
}

// ---------------- rmsnorm normalize-only (scale from fused SSQ table) ----------
template <int SPLIT>
__global__ void __launch_bounds__(256) k_rmsnorm(const float* __restrict__ in,
                                                 const float* __restrict__ rmsw,
                                                 const float* __restrict__ ssq,
                                                 ushort_t* __restrict__ NBh,
                                                 ushort_t* __restrict__ NBl) {
  extern __shared__ float wT[];  // 64*257 floats
  int n = blockIdx.x, t = threadIdx.x;
  const float* p = in + (size_t)n * 16384;
  for (int k = 0; k < 64; ++k) {
    int i = k * 256 + t;  // i = c*64 + j
    wT[(i & 63) * 257 + (i >> 6)] = rmsw[i];
  }
  float scale = 1.0f / sqrtf(ssq[n] / 16384.f + 1.1920929e-07f);
  __syncthreads();
  ushort_t* oh = NBh + (size_t)n * 16384;
  ushort_t* ol = NBl + (size_t)n * 16384;
  for (int j = 0; j < 64; ++j) {
    int i = j * 256 + t;
    float v = p[i] * scale * wT[j * 257 + t];
    ushort_t h = f2bs(v);
    oh[i] = h;
    if (SPLIT) ol[i] = f2bs(v - bs2f(h));
  }
}

// ---------------- VQ (coalesced embT scores; fused q-SSQ) ----------------
__global__ void __launch_bounds__(256) k_vq(const float* __restrict__ enc,
                                            const float* __restrict__ embT,
                                            const float* __restrict__ emb,
                                            const float* __restrict__ enorm,
                                            float* __restrict__ q, float* __restrict__ sse,
                                            float* __restrict__ ssq4) {
  __shared__ float z[16][256];
  __shared__ float sc[512 * 16];
  __shared__ float bv[16][16];
  __shared__ int bi[16][16];
  __shared__ int idxs[16];
  int T0 = blockIdx.x * 16;
  int t = threadIdx.x;
  for (int j = 0; j < 16; ++j) z[j][t] = enc[(size_t)(T0 + j) * 256 + t];
  __syncthreads();
  float d0[16], d1[16];
#pragma unroll
  for (int j = 0; j < 16; ++j) { d0[j] = 0.f; d1[j] = 0.f; }
  for (int c4 = 0; c4 < 64; ++c4) {
    const float* eb = embT + (size_t)(c4 * 4) * 512 + t;  // [c][code] -> coalesced
    float e00 = eb[0], f00 = eb[256];
    float e01 = eb[512], f01 = eb[768];
    float e02 = eb[1024], f02 = eb[1280];
    float e03 = eb[1536], f03 = eb[1792];
#pragma unroll
    for (int j = 0; j < 16; ++j) {
      float4 zv = *(const float4*)&z[j][c4 * 4];
      d0[j] += zv.x * e00 + zv.y * e01 + zv.z * e02 + zv.w * e03;
      d1[j] += zv.x * f00 + zv.y * f01 + zv.z * f02 + zv.w * f03;
    }
  }
  float en0 = enorm[t], en1 = enorm[t + 256];
#pragma unroll
  for (int j = 0; j < 16; ++j) {
    sc[t * 16 + j] = en0 - 2.f * d0[j];
    sc[(t + 256) * 16 + j] = en1 - 2.f * d1[j];
  }
  __syncthreads();
  {
    int j = t & 15, chunk = t >> 4;
    float best = 3.4e38f;
    int bidx = 0;
    int c0 = chunk * 32;
    for (int cc = 0; cc < 32; ++cc) {
      float v = sc[(c0 + cc) * 16 + j];
      if (v < best) { best = v; bidx = c0 + cc; }
    }
    bv[chunk][j] = best;
    bi[chunk][j] = bidx;
  }
  __syncthreads();
  if (t < 16) {
    float best = 3.4e38f;
    int bidx = 0;
    for (int c = 0; c < 16; ++c) {
      float v = bv[c][t];
      if (v < best) { best = v; bidx = bi[c][t]; }
    }
    idxs[t] = bidx;
  }
  __syncthreads();
  float sq = 0.f, sqq = 0.f;
  for (int j = 0; j < 16; ++j) {
    float e = emb[(size_t)idxs[j] * 256 + t];
    q[(size_t)(T0 + j) * 256 + t] = e;
    float d = z[j][t] - e;
    sq += d * d;
    sqq += e * e;
  }
  __syncthreads();
  sc[t] = sq;
  __syncthreads();
  for (int k = 128; k > 0; k >>= 1) {
    if (t < k) sc[t] += sc[t + k];
    __syncthreads();
  }
  if (t == 0) atomicAdd(sse, sc[0]);
  __syncthreads();
  sc[t] = sqq;
  __syncthreads();
  for (int k = 128; k > 0; k >>= 1) {
    if (t < k) sc[t] += sc[t + k];
    __syncthreads();
  }
  if (t == 0) atomicAdd(&ssq4[blockIdx.x >> 2], sc[0]);
}

// ---------------- deconv2 + reconst loss ----------------
__global__ void __launch_bounds__(256) k_deconv2(const ushort_t* __restrict__ in,
                                                 const float* __restrict__ wT,
                                                 const float* __restrict__ bias,
                                                 const float* __restrict__ x,
                                                 float* __restrict__ dec,
                                                 float* __restrict__ sse) {
  __shared__ float patch[9216];
  __shared__ float red[768];
  int blk = blockIdx.x;
  int oy = blk & 31, n = blk >> 5;
  int t = threadIdx.x;
  int py = (oy + 1) & 1;
  int dy = (oy + 1 - py) >> 1;
  for (int it = 0; it < 36; ++it) {
    int s = it / 18, col = it - s * 18;
    int ix = col - 1, iy = dy - 1 + s;
    float v = 0.f;
    if ((unsigned)iy < 16u && (unsigned)ix < 16u)
      v = bs2f(in[(size_t)((n << 8) + iy * 16 + ix) * 256 + t]);
    patch[(t * 2 + s) * 18 + col] = v;
  }
  __syncthreads();
  int ox = t & 31, g = t >> 5;
  int px = (ox + 1) & 1;
  int dx = (ox + 1 - px) >> 1;
  int k00 = ((py + 2) * 4 + px + 2) * 3;
  int k01 = k00 - 6;
  int k10 = (py * 4 + px + 2) * 3;
  int k11 = k10 - 6;
  float a0 = 0.f, a1 = 0.f, a2 = 0.f;
  for (int ic = g * 32; ic < g * 32 + 32; ++ic) {
    const float* pp = patch + ic * 36;
    float v00 = pp[dx], v01 = pp[dx + 1], v10 = pp[18 + dx], v11 = pp[18 + dx + 1];
    const float* ww = wT + ic * 48;
    a0 += v00 * ww[k00 + 0] + v01 * ww[k01 + 0] + v10 * ww[k10 + 0] + v11 * ww[k11 + 0];
    a1 += v00 * ww[k00 + 1] + v01 * ww[k01 + 1] + v10 * ww[k10 + 1] + v11 * ww[k11 + 1];
    a2 += v00 * ww[k00 + 2] + v01 * ww[k01 + 2] + v10 * ww[k10 + 2] + v11 * ww[k11 + 2];
  }
  red[t * 3 + 0] = a0;
  red[t * 3 + 1] = a1;
  red[t * 3 + 2] = a2;
  __syncthreads();
  float sq = 0.f;
  if (t < 96) {
    int ox2 = t & 31, oc = t >> 5;
    float v = bias[oc];
#pragma unroll
    for (int g2 = 0; g2 < 8; ++g2) v += red[(g2 * 32 + ox2) * 3 + oc];
    int oi = ((n * 3 + oc) * 32 + oy) * 32 + ox2;
    dec[oi] = v;
    float d = v - x[oi];
    sq = d * d;
  }
  __syncthreads();
  red[t] = sq;
  __syncthreads();
  for (int k = 128; k > 0; k >>= 1) {
    if (t < k) red[t] += red[t + k];
    __syncthreads();
  }
  if (t == 0) atomicAdd(sse, red[0]);
}

__global__ void k_final(const float* __restrict__ acc, float* __restrict__ out) {
  if (threadIdx.x == 0 && blockIdx.x == 0) {
    float vq = acc[0] / 4194304.f;
    float rec = acc[1] / 786432.f;
    out[0] = rec + 2.f * vq;
    out[1] = rec;
    out[2] = vq;
    out[3] = vq;
  }
}

extern "C" void kernel_launch(void* const* d_in, const int* in_sizes, int n_in,
                              void* d_out, int out_size, void* d_ws, size_t ws_size,
                              hipStream_t stream) {
  (void)in_sizes; (void)n_in; (void)out_size; (void)ws_size;
  const float* x = (const float*)d_in[0];
  const float* ew1 = (const float*)d_in[1];
  const float* eb1 = (const float*)d_in[2];
  const float* ew2 = (const float*)d_in[3];
  const float* eb2 = (const float*)d_in[4];
  const float* rmsw = (const float*)d_in[5];
  const float* r3w = (const float*)d_in[6];
  const float* r3b = (const float*)d_in[7];
  const float* r1w = (const float*)d_in[8];
  const float* r1b = (const float*)d_in[9];
  const float* emb = (const float*)d_in[10];
  const float* dw1 = (const float*)d_in[11];
  const float* db1 = (const float*)d_in[12];
  const float* dw2 = (const float*)d_in[13];
  const float* db2 = (const float*)d_in[14];
  float* out = (float*)d_out;

  float* wsf = (float*)d_ws;
  float* P = wsf + OFF_P;
  float* enorm = wsf + OFF_ENORM;
  float* wTd2 = wsf + OFF_WTD2;
  float* acc = wsf + OFF_ACC;
  float* zrowf = wsf + OFF_ZROW;
  float* embT = wsf + OFF_EMBT;
  float* ssq = wsf + OFF_SSQ;
  ushort_t* sb = (ushort_t*)(wsf + OFF_SHORT);
  ushort_t* H1H = sb + SO_H1H;
  ushort_t* H1L = sb + SO_H1L;
  float* Qf = (float*)(sb + SO_H1L);
  ushort_t* NBH = sb + SO_NBH;
  ushort_t* NBL = sb + SO_NBL;
  ushort_t* A1H = NBH;
  ushort_t* A1L = NBL;
  ushort_t* QB = NBL;
  ushort_t* W1H = sb + SO_W1H;
  ushort_t* W1L = sb + SO_W1L;
  ushort_t* W2H = sb + SO_W2H;
  ushort_t* W2L = sb + SO_W2L;
  ushort_t* W3EH = sb + SO_W3EH;
  ushort_t* W3EL = sb + SO_W3EL;
  ushort_t* W3D = sb + SO_W3D;
  ushort_t* W1REH = sb + SO_W1REH;
  ushort_t* W1REL = sb + SO_W1REL;
  ushort_t* W1RD = sb + SO_W1RD;
  ushort_t* WD1 = sb + SO_WD1;
  const ushort_t* zrow = (const ushort_t*)zrowf;
  const size_t RMS_LDS = 64 * 257 * sizeof(float);

  k_prep<<<35443, 256, 0, stream>>>(x, ew1, ew2, r3w, r1w, dw1, dw2, emb,
                                    W1H, W1L, W2H, W2L, W3EH, W3EL, W3D,
                                    W1REH, W1REL, W1RD, WD1, wTd2, enorm, acc,
                                    zrowf, embT, ssq, A1H, A1L);

  // conv1 (split, K=64, SWZ)
  k_gemm<0, 4, 1, 1, 0><<<dim3(2048), 256, 0, stream>>>(
      A1H, A1L, W1H, W1L, 64, eb1, nullptr, nullptr, H1H, H1L, zrow, nullptr);
  // conv2 (split, K=4096, SWZ) -> P, ssq slot 0
  k_gemm<1, 1, 1, 1, 1><<<dim3(512), 256, 0, stream>>>(
      H1H, H1L, W2H, W2L, 4096, eb2, nullptr, P, nullptr, nullptr, zrow, ssq + 0);
  for (int rb = 0; rb < 2; ++rb) {
    k_rmsnorm<1><<<256, 256, RMS_LDS, stream>>>(
        P, rmsw + (size_t)(rb * 2 + 0) * 16384, ssq + (rb * 2 + 0) * 256, NBH, NBL);
    if (rb == 0)
      k_gemm<2, 2, 1, 1, 1><<<dim3(512), 256, 0, stream>>>(
          NBH, NBL, W3EH, W3EL, 2304, r3b, P, Qf, nullptr, nullptr, zrow, ssq + 256);
    else
      k_gemm<2, 2, 1, 1, 1><<<dim3(512), 256, 0, stream>>>(
          NBH, NBL, W3EH + 589824, W3EL + 589824, 2304, r3b + 256, P, Qf, nullptr,
          nullptr, zrow, ssq + 768);
    k_rmsnorm<1><<<256, 256, RMS_LDS, stream>>>(
        Qf, rmsw + (size_t)(rb * 2 + 1) * 16384, ssq + (rb * 2 + 1) * 256, NBH, NBL);
    if (rb == 0)
      k_gemm<0, 2, 1, 1, 1><<<dim3(512), 256, 0, stream>>>(
          NBH, NBL, W1REH, W1REL, 256, r1b, Qf, P, nullptr, nullptr, zrow, ssq + 512);
    else
      k_gemm<0, 2, 1, 1, 0><<<dim3(512), 256, 0, stream>>>(
          NBH, NBL, W1REH + 65536, W1REL + 65536, 256, r1b + 256, Qf, P, nullptr,
          nullptr, zrow, nullptr);
  }

  // VQ: P -> Qf (q), sse -> acc[0], q-ssq -> slot 4
  k_vq<<<1024, 256, 0, stream>>>(P, embT, emb, enorm, Qf, acc + 0, ssq + 1024);

  for (int rb = 2; rb < 4; ++rb) {
    k_rmsnorm<0><<<256, 256, RMS_LDS, stream>>>(
        Qf, rmsw + (size_t)(rb * 2 + 0) * 16384, ssq + (rb * 2 + 0) * 256, NBH, NBL);
    if (rb == 2)
      k_gemm<2, 2, 0, 1, 1><<<dim3(512), 256, 0, stream>>>(
          NBH, nullptr, W3D, nullptr, 2304, r3b + 2 * 256, Qf, P, nullptr, nullptr,
          zrow, ssq + 1280);
    else
      k_gemm<2, 2, 0, 1, 1><<<dim3(512), 256, 0, stream>>>(
          NBH, nullptr, W3D + 589824, nullptr, 2304, r3b + 3 * 256, Qf, P, nullptr,
          nullptr, zrow, ssq + 1792);
    k_rmsnorm<0><<<256, 256, RMS_LDS, stream>>>(
        P, rmsw + (size_t)(rb * 2 + 1) * 16384, ssq + (rb * 2 + 1) * 256, NBH, NBL);
    if (rb == 3) {
      k_gemm<0, 5, 0, 1, 0><<<dim3(512), 256, 0, stream>>>(
          NBH, nullptr, W1RD + 65536, nullptr, 256, r1b + 3 * 256, P, Qf, QB, nullptr,
          zrow, nullptr);
    } else {
      k_gemm<0, 2, 0, 1, 1><<<dim3(512), 256, 0, stream>>>(
          NBH, nullptr, W1RD, nullptr, 256, r1b + 2 * 256, P, Qf, nullptr, nullptr,
          zrow, ssq + 1536);
    }
  }

  // deconv1 (plain, K=1024, 4 parity classes via z; unswizzled)
  k_gemm<3, 3, 0, 0, 0><<<dim3(128, 4, 4), 256, 0, stream>>>(
      QB, nullptr, WD1, nullptr, 1024, db1, nullptr, nullptr, H1H, nullptr, zrow, nullptr);

  k_deconv2<<<8192, 256, 0, stream>>>(H1H, wTd2, db2, x, out + 4, acc + 1);
  k_final<<<1, 64, 0, stream>>>(acc, out);
}

// Round 6
// 1086.286 us; speedup vs baseline: 1.5323x; 1.5323x over previous
//
#include <hip/hip_runtime.h>
#include <hip/hip_bf16.h>

typedef unsigned short ushort_t;
typedef __attribute__((ext_vector_type(8))) short short8v;
typedef __attribute__((ext_vector_type(4))) float f32x4;

__device__ __forceinline__ ushort_t f2bs(float v) {
  union { __hip_bfloat16 h; ushort_t u; } cv;
  cv.h = __float2bfloat16(v);
  return cv.u;
}
__device__ __forceinline__ float bs2f(ushort_t u) {
  union { ushort_t u; __hip_bfloat16 h; } cv;
  cv.u = u;
  return __bfloat162float(cv.h);
}

__device__ __forceinline__ void glds16(const ushort_t* g, ushort_t* l) {
  __builtin_amdgcn_global_load_lds(
      (const __attribute__((address_space(1))) unsigned int*)(uintptr_t)g,
      (__attribute__((address_space(3))) unsigned int*)(unsigned int)(uintptr_t)l,
      16, 0, 0);
}

// ---------------- workspace layout ----------------
static constexpr size_t OFF_P = 0;
static constexpr size_t OFF_ENORM = 4194304;
static constexpr size_t OFF_WTD2 = 4194816;
static constexpr size_t OFF_ACC = 4207360;
static constexpr size_t OFF_ZROW = 4207368;
static constexpr size_t OFF_EMBT = 4207432;   // fp32 embT [c=256][code=512]
static constexpr size_t OFF_SSQ = 4338504;    // 8 slots x 256 samples
static constexpr size_t OFF_SHORT = 4340552;  // 16B aligned (x4 bytes)
static constexpr size_t SO_H1H = 0;
static constexpr size_t SO_H1L = 16777216;
static constexpr size_t SO_NBH = 33554432;
static constexpr size_t SO_NBL = 37748736;
static constexpr size_t SO_W1H = 41943040;
static constexpr size_t SO_W1L = 41959424;
static constexpr size_t SO_W2H = 41975808;
static constexpr size_t SO_W2L = 43024384;
static constexpr size_t SO_W3EH = 44072960;
static constexpr size_t SO_W3EL = 45252608;
static constexpr size_t SO_W3D = 46432256;
static constexpr size_t SO_W1REH = 47611904;
static constexpr size_t SO_W1REL = 47742976;
static constexpr size_t SO_W1RD = 47874048;
static constexpr size_t SO_WD1 = 48005120;

__device__ __forceinline__ void split_store(float v, ushort_t* hi, ushort_t* lo, size_t i) {
  ushort_t h = f2bs(v);
  hi[i] = h;
  lo[i] = f2bs(v - bs2f(h));
}

// ---------------- fused prep ----------------
// ranges: [0,64) w1 | [64,4160) w2 | [4160,8768) w3e | [8768,13376) w3d
// [13376,13888) w1re | [13888,14400) w1rd | [14400,18496) wd1 | [18496,18544) dec2
// [18544,18546) enorm | 18546 zero | [18547,34931) conv1 im2col (16384 blocks EXACT)
// [34931,35443) embT
__global__ void __launch_bounds__(256) k_prep(
    const float* __restrict__ x, const float* __restrict__ ew1,
    const float* __restrict__ ew2, const float* __restrict__ r3w,
    const float* __restrict__ r1w, const float* __restrict__ dw1,
    const float* __restrict__ dw2, const float* __restrict__ emb,
    ushort_t* __restrict__ W1H, ushort_t* __restrict__ W1L,
    ushort_t* __restrict__ W2H, ushort_t* __restrict__ W2L,
    ushort_t* __restrict__ W3EH, ushort_t* __restrict__ W3EL,
    ushort_t* __restrict__ W3D, ushort_t* __restrict__ W1REH,
    ushort_t* __restrict__ W1REL, ushort_t* __restrict__ W1RD,
    ushort_t* __restrict__ WD1, float* __restrict__ wTd2,
    float* __restrict__ enorm, float* __restrict__ acc, float* __restrict__ zrow,
    float* __restrict__ embT, float* __restrict__ ssq,
    ushort_t* __restrict__ A1H, ushort_t* __restrict__ A1L) {
  int b = blockIdx.x, t = threadIdx.x;
  if (b < 64) {
    int i = b * 256 + t;
    int oc = i >> 6, k = i & 63;
    float v = 0.f;
    if (k < 48) {
      int tap = k / 3, ic = k - 3 * tap;
      v = ew1[(oc * 3 + ic) * 16 + tap];
    }
    split_store(v, W1H, W1L, i);
  } else if (b < 4160) {
    int i = (b - 64) * 256 + t;
    int oc = i >> 12, k = i & 4095;
    int tap = k >> 8, ic = k & 255;
    split_store(ew2[(oc * 256 + ic) * 16 + tap], W2H, W2L, i);
  } else if (b < 8768) {
    int i = (b - 4160) * 256 + t;
    int rb = i / 589824, r2 = i - rb * 589824;
    int oc = r2 / 2304, k = r2 - oc * 2304;
    int r9 = k >> 8, ic = k & 255;
    split_store(r3w[((rb * 256 + oc) * 256 + ic) * 9 + r9], W3EH, W3EL, i);
  } else if (b < 13376) {
    int i = (b - 8768) * 256 + t;
    int rb = i / 589824, r2 = i - rb * 589824;
    int oc = r2 / 2304, k = r2 - oc * 2304;
    int r9 = k >> 8, ic = k & 255;
    W3D[i] = f2bs(r3w[(((rb + 2) * 256 + oc) * 256 + ic) * 9 + r9]);
  } else if (b < 13888) {
    int i = (b - 13376) * 256 + t;
    split_store(r1w[i], W1REH, W1REL, i);
  } else if (b < 14400) {
    int i = (b - 13888) * 256 + t;
    W1RD[i] = f2bs(r1w[2 * 65536 + i]);
  } else if (b < 18496) {
    int i = (b - 14400) * 256 + t;
    int cls = i >> 18, r2 = i & 262143;
    int oc = r2 >> 10, k = r2 & 1023;
    int tap = k >> 8, ic = k & 255;
    int s = tap >> 1, sx = tap & 1;
    int py = cls >> 1, px = cls & 1;
    int ky = py + 2 - 2 * s, kx = px + 2 - 2 * sx;
    WD1[i] = f2bs(dw1[(ic * 256 + oc) * 16 + ky * 4 + kx]);
  } else if (b < 18544) {
    int i = (b - 18496) * 256 + t;
    if (i < 12288) {
      int kyx = i & 15;
      int r = i >> 4;
      int oc = r % 3;
      int ic = r / 3;
      wTd2[(ic * 16 + kyx) * 3 + oc] = dw2[i];
    }
  } else if (b < 18546) {
    int e = (b - 18544) * 256 + t;
    float s = 0.f;
    for (int c = 0; c < 256; ++c) {
      float v = emb[e * 256 + c];
      s += v * v;
    }
    enorm[e] = s;
  } else if (b == 18546) {
    if (t < 2) acc[t] = 0.f;
    if (t < 64) zrow[t] = 0.f;
    for (int k = t; k < 2048; k += 256) ssq[k] = 0.f;
  } else if (b < 34931) {  // conv1 im2col: exactly 16384 blocks
    int i = (b - 18547) * 256 + t;
    int t1 = i >> 6, k = i & 63;
    float v = 0.f;
    if (k < 48) {
      int tap = k / 3, ic = k - 3 * tap;
      int n = t1 >> 8, oy = (t1 >> 4) & 15, ox = t1 & 15;
      int ky = tap >> 2, kx = tap & 3;
      int iy = 2 * oy - 1 + ky, ix = 2 * ox - 1 + kx;
      if ((unsigned)iy < 32u && (unsigned)ix < 32u)
        v = x[((n * 3 + ic) * 32 + iy) * 32 + ix];
    }
    split_store(v, A1H, A1L, i);
  } else {  // [34931, 35443): embT [c][code] fp32
    int i = (b - 34931) * 256 + t;
    int code = i >> 8, c = i & 255;
    embT[c * 512 + code] = emb[i];
  }
}

// ---------------- MFMA GEMM (full-width BN=256, BM=64, 8 waves, PIPE=3) ----
// Each block owns ALL 256 output channels for 64 rows -> A is staged exactly
// ONCE (no N-panel duplication; rounds 0-4 staged A 4x). All blocks read the
// SAME 32 KB B-slice per K-step near-simultaneously -> B staging is L2-hit
// traffic; with 1 block/CU (forced by 120 KB LDS) the per-XCD stream between
// im2col tap reuses is ~2.3 MB < 4 MB L2, so tap re-reads also hit L2. This
// attacks the measured invariant: time = staged L2-miss bytes / ~8 TB/s.
// Staging: wave w (of 8) issues 5 glds/step: 1 A (group w&3; w<4 H, w>=4 L)
// + B-H groups {2w,2w+1} + B-L groups {2w,2w+1}. Counted wait = vmcnt(5).
// Wave tile 32x64: m_off=(w&1)*32, n_off=(w>>1)*64, acc[2][4].
// SSQ: BM=64 = exactly one 64-token sample per block.
template <int MODE, int EPI, int STYLE, int SSQ>
__global__ __launch_bounds__(512) void k_gemm(const ushort_t* __restrict__ Ah,
                                              const ushort_t* __restrict__ Al,
                                              const ushort_t* __restrict__ Bh,
                                              const ushort_t* __restrict__ Bl, int K,
                                              const float* __restrict__ bias,
                                              const float* __restrict__ res,
                                              float* __restrict__ outf,
                                              ushort_t* __restrict__ outb,
                                              ushort_t* __restrict__ outb2,
                                              const ushort_t* __restrict__ zrow,
                                              float* __restrict__ ssqp) {
  constexpr int PIPE = 3;
  __shared__ __align__(16) ushort_t A0[PIPE][64 * 32];
  __shared__ __align__(16) ushort_t A1s[PIPE][64 * 32];
  __shared__ __align__(16) ushort_t B0[PIPE][256 * 32];
  __shared__ __align__(16) ushort_t B1[PIPE][256 * 32];
  const int t = threadIdx.x;
  const int w = t >> 6, l = t & 63;
  const int M0 = blockIdx.x * 64;
  int py = 0, px = 0;
  const ushort_t* Bb = Bh;
  if (MODE == 3) {
    int cls = blockIdx.z;
    py = cls >> 1;
    px = cls & 1;
    Bb = Bh + (size_t)cls * 262144;
  }
  const int srow = l & 15, chunk = l >> 4;
  const int fr = l & 15, quad = l >> 4;
  const int m_off = (w & 1) * 32, n_off = (w >> 1) * 64;
  const int mset = (m_off >> 4), nset = (n_off >> 4);

  // staging assignment
  const int aw = w & 3;              // A 16-row group this wave stages
  const bool aH = (w < 4);           // stage A-H (else A-L / A-hi-k)
  const int atok = M0 + aw * 16 + srow;
  const size_t bb0 = (size_t)(2 * w * 16 + srow) * K + chunk * 8;
  const size_t bb1 = (size_t)((2 * w + 1) * 16 + srow) * K + chunk * 8;

  f32x4 acc[2][4];
#pragma unroll
  for (int i = 0; i < 2; ++i)
#pragma unroll
    for (int j = 0; j < 4; ++j) acc[i][j] = (f32x4){0.f, 0.f, 0.f, 0.f};

  const int n1 = atok >> 6, oy1 = (atok >> 3) & 7, ox1 = atok & 7;
  const ushort_t* zp = zrow + chunk * 8;

  const int SUB = (STYLE == 1) ? 32 : 64;

  // persistent per-tap staging state (recomputed when (kk&255)==0)
  size_t r1s = 0;
  bool v1s = true;
  if (MODE == 0) r1s = (size_t)atok * K + chunk * 8;

  auto stage = [&](int kk, int s) {
    const ushort_t* pa;
    if (MODE == 0) {
      size_t o = r1s + kk;
      pa = aH ? (Ah + o) : ((STYLE == 1) ? (Al + o) : (Ah + o + 32));
    } else {
      if ((kk & 255) == 0) {
        int tap = kk >> 8;
        int iy, ix;
        unsigned lim;
        if (MODE == 1) {
          int ky = tap >> 2, kx = tap & 3;
          iy = 2 * oy1 - 1 + ky; ix = 2 * ox1 - 1 + kx;
          lim = 16u;
        } else if (MODE == 2) {
          int ky = tap / 3, kx = tap - ky * 3;
          iy = oy1 - 1 + ky; ix = ox1 - 1 + kx;
          lim = 8u;
        } else {
          int s2 = tap >> 1, sx = tap & 1;
          iy = oy1 + s2 - py; ix = ox1 + sx - px;
          lim = 8u;
        }
        v1s = ((unsigned)iy < lim && (unsigned)ix < lim);
        if (MODE == 1)
          r1s = (size_t)(((n1 << 8) + (iy << 4) + ix)) << 8;
        else
          r1s = (size_t)(((n1 << 6) + (iy << 3) + ix)) << 8;
      }
      int kin = (kk & 255) + chunk * 8;
      if (v1s)
        pa = aH ? (Ah + r1s + kin)
                : ((STYLE == 1) ? (Al + r1s + kin) : (Ah + r1s + kin + 32));
      else
        pa = zp;
    }
    size_t bo0 = bb0 + kk, bo1 = bb1 + kk;
    glds16(pa, (aH ? A0[s] : A1s[s]) + aw * 512);
    glds16(Bb + bo0, B0[s] + (2 * w) * 512);
    glds16(Bb + bo1, B0[s] + (2 * w + 1) * 512);
    glds16((STYLE == 1) ? (Bl + bo0) : (Bb + bo0 + 32), B1[s] + (2 * w) * 512);
    glds16((STYLE == 1) ? (Bl + bo1) : (Bb + bo1 + 32), B1[s] + (2 * w + 1) * 512);
  };

  auto compute = [&](int s) {
    short8v af0[2], af1[2], bf0[4], bf1[4];
#pragma unroll
    for (int mi = 0; mi < 2; ++mi) {
      af0[mi] = *(const short8v*)(A0[s] + (mset + mi) * 512 + quad * 128 + fr * 8);
      af1[mi] = *(const short8v*)(A1s[s] + (mset + mi) * 512 + quad * 128 + fr * 8);
    }
#pragma unroll
    for (int nj = 0; nj < 4; ++nj) {
      bf0[nj] = *(const short8v*)(B0[s] + (nset + nj) * 512 + quad * 128 + fr * 8);
      bf1[nj] = *(const short8v*)(B1[s] + (nset + nj) * 512 + quad * 128 + fr * 8);
    }
#pragma unroll
    for (int mi = 0; mi < 2; ++mi)
#pragma unroll
      for (int nj = 0; nj < 4; ++nj) {
        acc[mi][nj] =
            __builtin_amdgcn_mfma_f32_16x16x32_bf16(af0[mi], bf0[nj], acc[mi][nj], 0, 0, 0);
        if (STYLE == 1) {
          acc[mi][nj] =
              __builtin_amdgcn_mfma_f32_16x16x32_bf16(af1[mi], bf0[nj], acc[mi][nj], 0, 0, 0);
          acc[mi][nj] =
              __builtin_amdgcn_mfma_f32_16x16x32_bf16(af0[mi], bf1[nj], acc[mi][nj], 0, 0, 0);
        } else {
          acc[mi][nj] =
              __builtin_amdgcn_mfma_f32_16x16x32_bf16(af1[mi], bf1[nj], acc[mi][nj], 0, 0, 0);
        }
      }
  };

  // ---- counted-vmcnt pipeline (per-wave: 5 loads/step; <=10 in flight) ----
  {
    const int nt = K / SUB;
    stage(0, 0);
    int ns = 1;
    if (nt > 1) {
      stage(SUB, 1);
      ns = 2;
    }
    int cb = 0, sb2 = ns % PIPE;
    for (int tt = 0; tt < nt; ++tt) {
      if (ns > tt + 1) {
        asm volatile("s_waitcnt vmcnt(5)" ::: "memory");
      } else {
        asm volatile("s_waitcnt vmcnt(0)" ::: "memory");
      }
      asm volatile("s_barrier" ::: "memory");
      if (ns < nt) {
        stage(ns * SUB, sb2);
        ++ns;
        sb2 = (sb2 + 1 == PIPE) ? 0 : sb2 + 1;
      }
      compute(cb);
      cb = (cb + 1 == PIPE) ? 0 : cb + 1;
    }
  }

  float sq = 0.f;
#pragma unroll
  for (int mi = 0; mi < 2; ++mi) {
    int mrow = m_off + mi * 16 + quad * 4;
#pragma unroll
    for (int nj = 0; nj < 4; ++nj) {
      int col = n_off + nj * 16 + fr;
      float bv = bias[col];
#pragma unroll
      for (int i = 0; i < 4; ++i) {
        int m = M0 + mrow + i;
        float v = fmaxf(acc[mi][nj][i] + bv, 0.f);
        if (EPI == 1) {
          outf[(size_t)m * 256 + col] = v;
          if (SSQ) sq += v * v;
        } else if (EPI == 2) {
          size_t o = (size_t)m * 256 + col;
          float vv = res[o] + v;
          outf[o] = vv;
          if (SSQ) sq += vv * vv;
        } else if (EPI == 3) {
          int nn = m >> 6, jj = (m >> 3) & 7, ii = m & 7;
          int oy = 2 * jj + 1 - py, ox = 2 * ii + 1 - px;
          outb[(size_t)((nn << 8) + oy * 16 + ox) * 256 + col] = f2bs(v);
        } else if (EPI == 4) {
          size_t o = (size_t)m * 256 + col;
          ushort_t h = f2bs(v);
          outb[o] = h;
          outb2[o] = f2bs(v - bs2f(h));
        } else {  // EPI 5
          size_t o = (size_t)m * 256 + col;
          float vv = res[o] + v;
          outf[o] = vv;
          outb[o] = f2bs(vv);
        }
      }
    }
  }
  if (SSQ) {
#pragma unroll
    for (int off = 32; off > 0; off >>= 1) sq += __shfl_down(sq, off, 64);
    if (l == 0) atomicAdd(&ssqp[M0 >> 6], sq);
  }
}

// ---------------- rmsnorm normalize-only (scale from fused SSQ table) ----------
template <int SPLIT>
__global__ void __launch_bounds__(256) k_rmsnorm(const float* __restrict__ in,
                                                 const float* __restrict__ rmsw,
                                                 const float* __restrict__ ssq,
                                                 ushort_t* __restrict__ NBh,
                                                 ushort_t* __restrict__ NBl) {
  extern __shared__ float wT[];  // 64*257 floats
  int n = blockIdx.x, t = threadIdx.x;
  const float* p = in + (size_t)n * 16384;
  for (int k = 0; k < 64; ++k) {
    int i = k * 256 + t;  // i = c*64 + j
    wT[(i & 63) * 257 + (i >> 6)] = rmsw[i];
  }
  float scale = 1.0f / sqrtf(ssq[n] / 16384.f + 1.1920929e-07f);
  __syncthreads();
  ushort_t* oh = NBh + (size_t)n * 16384;
  ushort_t* ol = NBl + (size_t)n * 16384;
  for (int j = 0; j < 64; ++j) {
    int i = j * 256 + t;
    float v = p[i] * scale * wT[j * 257 + t];
    ushort_t h = f2bs(v);
    oh[i] = h;
    if (SPLIT) ol[i] = f2bs(v - bs2f(h));
  }
}

// ---------------- VQ (coalesced embT scores; fused q-SSQ) ----------------
__global__ void __launch_bounds__(256) k_vq(const float* __restrict__ enc,
                                            const float* __restrict__ embT,
                                            const float* __restrict__ emb,
                                            const float* __restrict__ enorm,
                                            float* __restrict__ q, float* __restrict__ sse,
                                            float* __restrict__ ssq4) {
  __shared__ float z[16][256];
  __shared__ float sc[512 * 16];
  __shared__ float bv[16][16];
  __shared__ int bi[16][16];
  __shared__ int idxs[16];
  int T0 = blockIdx.x * 16;
  int t = threadIdx.x;
  for (int j = 0; j < 16; ++j) z[j][t] = enc[(size_t)(T0 + j) * 256 + t];
  __syncthreads();
  float d0[16], d1[16];
#pragma unroll
  for (int j = 0; j < 16; ++j) { d0[j] = 0.f; d1[j] = 0.f; }
  for (int c4 = 0; c4 < 64; ++c4) {
    const float* eb = embT + (size_t)(c4 * 4) * 512 + t;  // [c][code] -> coalesced
    float e00 = eb[0], f00 = eb[256];
    float e01 = eb[512], f01 = eb[768];
    float e02 = eb[1024], f02 = eb[1280];
    float e03 = eb[1536], f03 = eb[1792];
#pragma unroll
    for (int j = 0; j < 16; ++j) {
      float4 zv = *(const float4*)&z[j][c4 * 4];
      d0[j] += zv.x * e00 + zv.y * e01 + zv.z * e02 + zv.w * e03;
      d1[j] += zv.x * f00 + zv.y * f01 + zv.z * f02 + zv.w * f03;
    }
  }
  float en0 = enorm[t], en1 = enorm[t + 256];
#pragma unroll
  for (int j = 0; j < 16; ++j) {
    sc[t * 16 + j] = en0 - 2.f * d0[j];
    sc[(t + 256) * 16 + j] = en1 - 2.f * d1[j];
  }
  __syncthreads();
  {
    int j = t & 15, chunk = t >> 4;
    float best = 3.4e38f;
    int bidx = 0;
    int c0 = chunk * 32;
    for (int cc = 0; cc < 32; ++cc) {
      float v = sc[(c0 + cc) * 16 + j];
      if (v < best) { best = v; bidx = c0 + cc; }
    }
    bv[chunk][j] = best;
    bi[chunk][j] = bidx;
  }
  __syncthreads();
  if (t < 16) {
    float best = 3.4e38f;
    int bidx = 0;
    for (int c = 0; c < 16; ++c) {
      float v = bv[c][t];
      if (v < best) { best = v; bidx = bi[c][t]; }
    }
    idxs[t] = bidx;
  }
  __syncthreads();
  float sq = 0.f, sqq = 0.f;
  for (int j = 0; j < 16; ++j) {
    float e = emb[(size_t)idxs[j] * 256 + t];
    q[(size_t)(T0 + j) * 256 + t] = e;
    float d = z[j][t] - e;
    sq += d * d;
    sqq += e * e;
  }
  __syncthreads();
  sc[t] = sq;
  __syncthreads();
  for (int k = 128; k > 0; k >>= 1) {
    if (t < k) sc[t] += sc[t + k];
    __syncthreads();
  }
  if (t == 0) atomicAdd(sse, sc[0]);
  __syncthreads();
  sc[t] = sqq;
  __syncthreads();
  for (int k = 128; k > 0; k >>= 1) {
    if (t < k) sc[t] += sc[t + k];
    __syncthreads();
  }
  if (t == 0) atomicAdd(&ssq4[blockIdx.x >> 2], sc[0]);
}

// ---------------- deconv2 + reconst loss ----------------
__global__ void __launch_bounds__(256) k_deconv2(const ushort_t* __restrict__ in,
                                                 const float* __restrict__ wT,
                                                 const float* __restrict__ bias,
                                                 const float* __restrict__ x,
                                                 float* __restrict__ dec,
                                                 float* __restrict__ sse) {
  __shared__ float patch[9216];
  __shared__ float red[768];
  int blk = blockIdx.x;
  int oy = blk & 31, n = blk >> 5;
  int t = threadIdx.x;
  int py = (oy + 1) & 1;
  int dy = (oy + 1 - py) >> 1;
  for (int it = 0; it < 36; ++it) {
    int s = it / 18, col = it - s * 18;
    int ix = col - 1, iy = dy - 1 + s;
    float v = 0.f;
    if ((unsigned)iy < 16u && (unsigned)ix < 16u)
      v = bs2f(in[(size_t)((n << 8) + iy * 16 + ix) * 256 + t]);
    patch[(t * 2 + s) * 18 + col] = v;
  }
  __syncthreads();
  int ox = t & 31, g = t >> 5;
  int px = (ox + 1) & 1;
  int dx = (ox + 1 - px) >> 1;
  int k00 = ((py + 2) * 4 + px + 2) * 3;
  int k01 = k00 - 6;
  int k10 = (py * 4 + px + 2) * 3;
  int k11 = k10 - 6;
  float a0 = 0.f, a1 = 0.f, a2 = 0.f;
  for (int ic = g * 32; ic < g * 32 + 32; ++ic) {
    const float* pp = patch + ic * 36;
    float v00 = pp[dx], v01 = pp[dx + 1], v10 = pp[18 + dx], v11 = pp[18 + dx + 1];
    const float* ww = wT + ic * 48;
    a0 += v00 * ww[k00 + 0] + v01 * ww[k01 + 0] + v10 * ww[k10 + 0] + v11 * ww[k11 + 0];
    a1 += v00 * ww[k00 + 1] + v01 * ww[k01 + 1] + v10 * ww[k10 + 1] + v11 * ww[k11 + 1];
    a2 += v00 * ww[k00 + 2] + v01 * ww[k01 + 2] + v10 * ww[k10 + 2] + v11 * ww[k11 + 2];
  }
  red[t * 3 + 0] = a0;
  red[t * 3 + 1] = a1;
  red[t * 3 + 2] = a2;
  __syncthreads();
  float sq = 0.f;
  if (t < 96) {
    int ox2 = t & 31, oc = t >> 5;
    float v = bias[oc];
#pragma unroll
    for (int g2 = 0; g2 < 8; ++g2) v += red[(g2 * 32 + ox2) * 3 + oc];
    int oi = ((n * 3 + oc) * 32 + oy) * 32 + ox2;
    dec[oi] = v;
    float d = v - x[oi];
    sq = d * d;
  }
  __syncthreads();
  red[t] = sq;
  __syncthreads();
  for (int k = 128; k > 0; k >>= 1) {
    if (t < k) red[t] += red[t + k];
    __syncthreads();
  }
  if (t == 0) atomicAdd(sse, red[0]);
}

__global__ void k_final(const float* __restrict__ acc, float* __restrict__ out) {
  if (threadIdx.x == 0 && blockIdx.x == 0) {
    float vq = acc[0] / 4194304.f;
    float rec = acc[1] / 786432.f;
    out[0] = rec + 2.f * vq;
    out[1] = rec;
    out[2] = vq;
    out[3] = vq;
  }
}

extern "C" void kernel_launch(void* const* d_in, const int* in_sizes, int n_in,
                              void* d_out, int out_size, void* d_ws, size_t ws_size,
                              hipStream_t stream) {
  (void)in_sizes; (void)n_in; (void)out_size; (void)ws_size;
  const float* x = (const float*)d_in[0];
  const float* ew1 = (const float*)d_in[1];
  const float* eb1 = (const float*)d_in[2];
  const float* ew2 = (const float*)d_in[3];
  const float* eb2 = (const float*)d_in[4];
  const float* rmsw = (const float*)d_in[5];
  const float* r3w = (const float*)d_in[6];
  const float* r3b = (const float*)d_in[7];
  const float* r1w = (const float*)d_in[8];
  const float* r1b = (const float*)d_in[9];
  const float* emb = (const float*)d_in[10];
  const float* dw1 = (const float*)d_in[11];
  const float* db1 = (const float*)d_in[12];
  const float* dw2 = (const float*)d_in[13];
  const float* db2 = (const float*)d_in[14];
  float* out = (float*)d_out;

  float* wsf = (float*)d_ws;
  float* P = wsf + OFF_P;
  float* enorm = wsf + OFF_ENORM;
  float* wTd2 = wsf + OFF_WTD2;
  float* acc = wsf + OFF_ACC;
  float* zrowf = wsf + OFF_ZROW;
  float* embT = wsf + OFF_EMBT;
  float* ssq = wsf + OFF_SSQ;
  ushort_t* sb = (ushort_t*)(wsf + OFF_SHORT);
  ushort_t* H1H = sb + SO_H1H;
  ushort_t* H1L = sb + SO_H1L;
  float* Qf = (float*)(sb + SO_H1L);
  ushort_t* NBH = sb + SO_NBH;
  ushort_t* NBL = sb + SO_NBL;
  ushort_t* A1H = NBH;
  ushort_t* A1L = NBL;
  ushort_t* QB = NBL;
  ushort_t* W1H = sb + SO_W1H;
  ushort_t* W1L = sb + SO_W1L;
  ushort_t* W2H = sb + SO_W2H;
  ushort_t* W2L = sb + SO_W2L;
  ushort_t* W3EH = sb + SO_W3EH;
  ushort_t* W3EL = sb + SO_W3EL;
  ushort_t* W3D = sb + SO_W3D;
  ushort_t* W1REH = sb + SO_W1REH;
  ushort_t* W1REL = sb + SO_W1REL;
  ushort_t* W1RD = sb + SO_W1RD;
  ushort_t* WD1 = sb + SO_WD1;
  const ushort_t* zrow = (const ushort_t*)zrowf;
  const size_t RMS_LDS = 64 * 257 * sizeof(float);

  k_prep<<<35443, 256, 0, stream>>>(x, ew1, ew2, r3w, r1w, dw1, dw2, emb,
                                    W1H, W1L, W2H, W2L, W3EH, W3EL, W3D,
                                    W1REH, W1REL, W1RD, WD1, wTd2, enorm, acc,
                                    zrowf, embT, ssq, A1H, A1L);

  // conv1 (split, K=64): M=65536 -> 1024 blocks
  k_gemm<0, 4, 1, 0><<<dim3(1024), 512, 0, stream>>>(
      A1H, A1L, W1H, W1L, 64, eb1, nullptr, nullptr, H1H, H1L, zrow, nullptr);
  // conv2 (split, K=4096) -> P, ssq slot 0
  k_gemm<1, 1, 1, 1><<<dim3(256), 512, 0, stream>>>(
      H1H, H1L, W2H, W2L, 4096, eb2, nullptr, P, nullptr, nullptr, zrow, ssq + 0);
  for (int rb = 0; rb < 2; ++rb) {
    k_rmsnorm<1><<<256, 256, RMS_LDS, stream>>>(
        P, rmsw + (size_t)(rb * 2 + 0) * 16384, ssq + (rb * 2 + 0) * 256, NBH, NBL);
    if (rb == 0)
      k_gemm<2, 2, 1, 1><<<dim3(256), 512, 0, stream>>>(
          NBH, NBL, W3EH, W3EL, 2304, r3b, P, Qf, nullptr, nullptr, zrow, ssq + 256);
    else
      k_gemm<2, 2, 1, 1><<<dim3(256), 512, 0, stream>>>(
          NBH, NBL, W3EH + 589824, W3EL + 589824, 2304, r3b + 256, P, Qf, nullptr,
          nullptr, zrow, ssq + 768);
    k_rmsnorm<1><<<256, 256, RMS_LDS, stream>>>(
        Qf, rmsw + (size_t)(rb * 2 + 1) * 16384, ssq + (rb * 2 + 1) * 256, NBH, NBL);
    if (rb == 0)
      k_gemm<0, 2, 1, 1><<<dim3(256), 512, 0, stream>>>(
          NBH, NBL, W1REH, W1REL, 256, r1b, Qf, P, nullptr, nullptr, zrow, ssq + 512);
    else
      k_gemm<0, 2, 1, 0><<<dim3(256), 512, 0, stream>>>(
          NBH, NBL, W1REH + 65536, W1REL + 65536, 256, r1b + 256, Qf, P, nullptr,
          nullptr, zrow, nullptr);
  }

  // VQ: P -> Qf (q), sse -> acc[0], q-ssq -> slot 4
  k_vq<<<1024, 256, 0, stream>>>(P, embT, emb, enorm, Qf, acc + 0, ssq + 1024);

  for (int rb = 2; rb < 4; ++rb) {
    k_rmsnorm<0><<<256, 256, RMS_LDS, stream>>>(
        Qf, rmsw + (size_t)(rb * 2 + 0) * 16384, ssq + (rb * 2 + 0) * 256, NBH, NBL);
    if (rb == 2)
      k_gemm<2, 2, 0, 1><<<dim3(256), 512, 0, stream>>>(
          NBH, nullptr, W3D, nullptr, 2304, r3b + 2 * 256, Qf, P, nullptr, nullptr,
          zrow, ssq + 1280);
    else
      k_gemm<2, 2, 0, 1><<<dim3(256), 512, 0, stream>>>(
          NBH, nullptr, W3D + 589824, nullptr, 2304, r3b + 3 * 256, Qf, P, nullptr,
          nullptr, zrow, ssq + 1792);
    k_rmsnorm<0><<<256, 256, RMS_LDS, stream>>>(
        P, rmsw + (size_t)(rb * 2 + 1) * 16384, ssq + (rb * 2 + 1) * 256, NBH, NBL);
    if (rb == 3) {
      k_gemm<0, 5, 0, 0><<<dim3(256), 512, 0, stream>>>(
          NBH, nullptr, W1RD + 65536, nullptr, 256, r1b + 3 * 256, P, Qf, QB, nullptr,
          zrow, nullptr);
    } else {
      k_gemm<0, 2, 0, 1><<<dim3(256), 512, 0, stream>>>(
          NBH, nullptr, W1RD, nullptr, 256, r1b + 2 * 256, P, Qf, nullptr, nullptr,
          zrow, ssq + 1536);
    }
  }

  // deconv1 (K=1024, 4 parity classes via z)
  k_gemm<3, 3, 0, 0><<<dim3(256, 1, 4), 512, 0, stream>>>(
      QB, nullptr, WD1, nullptr, 1024, db1, nullptr, nullptr, H1H, nullptr, zrow, nullptr);

  k_deconv2<<<8192, 256, 0, stream>>>(H1H, wTd2, db2, x, out + 4, acc + 1);
  k_final<<<1, 64, 0, stream>>>(acc, out);
}